// Round 9
// baseline (243.603 us; speedup 1.0000x reference)
//
#include <hip/hip_runtime.h>

#define NODES 50000
#define FEAT 128
#define EDGES 800000
#define GRAPHS 512
#define NB 196      // dst buckets (dst >> 8), 196*256 = 50176 >= NODES
#define CHUNK 4096
#define ABLK 196    // ceil(EDGES/CHUNK)
#define BCAP 8192   // max edges per bucket (mean 4082, max ~4400)

typedef unsigned int u32;
typedef unsigned short u16;
typedef __attribute__((ext_vector_type(8))) short short8;   // 8 bf16 = 4 VGPRs
typedef __attribute__((ext_vector_type(4))) float v4f;      // MFMA accumulator
typedef __attribute__((ext_vector_type(4))) u32 u32x4;
typedef __attribute__((ext_vector_type(2))) float f2;       // packed-fp32 pair

static __device__ __forceinline__ float bflo(u32 u){ return __uint_as_float(u << 16); }
static __device__ __forceinline__ float bfhi(u32 u){ return __uint_as_float(u & 0xffff0000u); }
static __device__ __forceinline__ u16 f2bf(float f){
  u32 u = __float_as_uint(f);
  u32 r = u + 0x7fffu + ((u >> 16) & 1u);
  return (u16)(r >> 16);
}
static __device__ __forceinline__ u32 packbf(float a, float b){
  return (u32)f2bf(a) | ((u32)f2bf(b) << 16);
}
static __device__ __forceinline__ f2 unpk(u32 u){ f2 r; r.x = bflo(u); r.y = bfhi(u); return r; }
static __device__ __forceinline__ f2 vmax2(f2 a, f2 b){ f2 r; r.x = fmaxf(a.x,b.x); r.y = fmaxf(a.y,b.y); return r; }

// ---------------- MFMA projection v3: barrier-free, no LDS -------------------
// A-frags load directly from x (row node0+mt*16+r16, cols k*32+quad*8..+7),
// B-frags for both matrices in registers. Epilogue pairs adjacent columns via
// shfl_xor(1) and stores packed-bf16 u32 (16 lanes/quad = one 64B line).
__global__ __launch_bounds__(256) void proj_kernel(
    const float* __restrict__ x, const float* __restrict__ Wsrc,
    const float* __restrict__ Wdst, u16* __restrict__ srcp, u16* __restrict__ dstp)
{
  const int t = threadIdx.x;
  const int node0 = blockIdx.x * 64;
  const int wave = t >> 6, lane = t & 63;
  const int r16 = lane & 15;
  const int quad = lane >> 4;
  const int n0 = wave * 32;
  const int odd = lane & 1;

  // B fragments for both matrices, fully in registers (L2-resident W).
  short8 bs[2][4], bd[2][4];
  #pragma unroll
  for (int nt = 0; nt < 2; ++nt){
    const int col = n0 + nt * 16 + r16;
    #pragma unroll
    for (int k = 0; k < 4; ++k){
      const float4* wp = (const float4*)(Wsrc + col * 128 + k * 32 + quad * 8);
      float4 w0 = wp[0], w1 = wp[1];
      u32x4 pk; pk.x = packbf(w0.x,w0.y); pk.y = packbf(w0.z,w0.w);
      pk.z = packbf(w1.x,w1.y); pk.w = packbf(w1.z,w1.w);
      bs[nt][k] = __builtin_bit_cast(short8, pk);
      const float4* vp = (const float4*)(Wdst + col * 128 + k * 32 + quad * 8);
      float4 v0 = vp[0], v1 = vp[1];
      u32x4 qk; qk.x = packbf(v0.x,v0.y); qk.y = packbf(v0.z,v0.w);
      qk.z = packbf(v1.x,v1.y); qk.w = packbf(v1.z,v1.w);
      bd[nt][k] = __builtin_bit_cast(short8, qk);
    }
  }

  u32* sp32 = (u32*)srcp;
  u32* dp32 = (u32*)dstp;
  #pragma unroll
  for (int mt = 0; mt < 4; ++mt){
    const int node_base = node0 + mt * 16;
    if (node_base >= NODES) break;
    // A fragments straight from x
    short8 afr[4];
    const float* xrow = x + (size_t)(node_base + r16) * 128 + quad * 8;
    #pragma unroll
    for (int k = 0; k < 4; ++k){
      const float4* xr = (const float4*)(xrow + k * 32);
      float4 a0 = xr[0], a1 = xr[1];
      u32x4 pk; pk.x = packbf(a0.x,a0.y); pk.y = packbf(a0.z,a0.w);
      pk.z = packbf(a1.x,a1.y); pk.w = packbf(a1.z,a1.w);
      afr[k] = __builtin_bit_cast(short8, pk);
    }
    v4f s0 = {0.f,0.f,0.f,0.f}, s1 = s0, d0 = s0, d1 = s0;
    #pragma unroll
    for (int k = 0; k < 4; ++k){
      s0 = __builtin_amdgcn_mfma_f32_16x16x32_bf16(afr[k], bs[0][k], s0, 0, 0, 0);
      s1 = __builtin_amdgcn_mfma_f32_16x16x32_bf16(afr[k], bs[1][k], s1, 0, 0, 0);
      d0 = __builtin_amdgcn_mfma_f32_16x16x32_bf16(afr[k], bd[0][k], d0, 0, 0, 0);
      d1 = __builtin_amdgcn_mfma_f32_16x16x32_bf16(afr[k], bd[1][k], d1, 0, 0, 0);
    }
    // C/D layout: row = node_base + quad*4 + r, col = n0+r16 (acc0) / n0+16+r16 (acc1).
    // Pair adjacent columns across lane-pairs -> one u32 store per (r, mat).
    const int uc = (n0 >> 1) + (odd ? 8 : 0) + (r16 >> 1);
    #pragma unroll
    for (int r = 0; r < 4; ++r){
      const size_t rowoff = (size_t)(node_base + quad * 4 + r) * 64 + uc;
      float q0 = __shfl_xor(s0[r], 1);
      float q1 = __shfl_xor(s1[r], 1);
      sp32[rowoff] = odd ? packbf(q1, s1[r]) : packbf(s0[r], q0);
      float p0 = __shfl_xor(d0[r], 1);
      float p1 = __shfl_xor(d1[r], 1);
      dp32[rowoff] = odd ? packbf(p1, d1[r]) : packbf(d0[r], p0);
    }
  }
}

// ---------------- CSR build: two-level LDS-bucketed counting sort ------------
__global__ __launch_bounds__(256) void bucket_hist_kernel(
    const int* __restrict__ ei, int* __restrict__ bcount)
{
  __shared__ int cnt[NB];
  const int b = blockIdx.x, t = threadIdx.x;
  for (int k = t; k < NB; k += 256) cnt[k] = 0;
  __syncthreads();
  const int e0 = b * CHUNK;
  const int e1 = (e0 + CHUNK < EDGES) ? e0 + CHUNK : EDGES;
  for (int e = e0 + t; e < e1; e += 256)
    atomicAdd(&cnt[ei[EDGES + e] >> 8], 1);
  __syncthreads();
  for (int k = t; k < NB; k += 256) bcount[k * ABLK + b] = cnt[k];
}

__global__ __launch_bounds__(256) void bucket_scan_kernel(
    int* __restrict__ bcount, int* __restrict__ bstart)
{
  __shared__ int tot[256];
  const int t = threadIdx.x;
  int total = 0;
  if (t < NB){
    int4* row = (int4*)(bcount + t * ABLK);
    int run = 0;
    #pragma unroll 7
    for (int q = 0; q < ABLK / 4; ++q){
      int4 c = row[q];
      int4 o;
      o.x = run; run += c.x;
      o.y = run; run += c.y;
      o.z = run; run += c.z;
      o.w = run; run += c.w;
      row[q] = o;
    }
    total = run;
  }
  tot[t] = total;
  __syncthreads();
  const int v = total;
  for (int off = 1; off < 256; off <<= 1){
    const int add = (t >= off) ? tot[t - off] : 0;
    __syncthreads();
    tot[t] += add;
    __syncthreads();
  }
  if (t < NB) bstart[t] = tot[t] - v;
  if (t == NB - 1) bstart[NB] = tot[t];
}

__global__ __launch_bounds__(256) void bucket_scatter_kernel(
    const int* __restrict__ ei, const int* __restrict__ obase,
    const int* __restrict__ bstart, u32* __restrict__ ebuf)
{
  __shared__ int cur[NB];
  const int b = blockIdx.x, t = threadIdx.x;
  for (int k = t; k < NB; k += 256) cur[k] = 0;
  __syncthreads();
  const int e0 = b * CHUNK;
  const int e1 = (e0 + CHUNK < EDGES) ? e0 + CHUNK : EDGES;
  for (int e = e0 + t; e < e1; e += 256){
    const int d = ei[EDGES + e];
    const int s = ei[e];
    const int k = d >> 8;
    const int r = atomicAdd(&cur[k], 1);
    ebuf[bstart[k] + obase[k * ABLK + b] + r] = (u32)s | ((u32)(d & 255) << 16);
  }
}

__global__ __launch_bounds__(256) void bucket_csr_kernel(
    const u32* __restrict__ ebuf, const int* __restrict__ bstart,
    int* __restrict__ row_start, int* __restrict__ srclist)
{
  __shared__ int cnt[256], excl[256], cur[256];
  __shared__ u32 loc[BCAP];
  const int k = blockIdx.x, t = threadIdx.x;
  const int base = bstart[k];
  int ne = bstart[k + 1] - base;
  if (ne > BCAP) ne = BCAP;
  cnt[t] = 0;
  __syncthreads();
  for (int j = t; j < ne; j += 256)
    atomicAdd(&cnt[(ebuf[base + j] >> 16) & 255], 1);
  __syncthreads();
  const int v = cnt[t];
  for (int off = 1; off < 256; off <<= 1){
    const int add = (t >= off) ? cnt[t - off] : 0;
    __syncthreads();
    cnt[t] += add;
    __syncthreads();
  }
  excl[t] = cnt[t] - v;
  cur[t] = cnt[t] - v;
  __syncthreads();
  const int node = k * 256 + t;
  if (node <= NODES) row_start[node] = base + excl[t];
  for (int j = t; j < ne; j += 256){
    const u32 e = ebuf[base + j];
    const int p = atomicAdd(&cur[(e >> 16) & 255], 1);
    loc[p] = e & 0xFFFFu;
  }
  __syncthreads();
  for (int j = t; j < ne; j += 256)
    srclist[base + j] = (int)loc[j];
}

// ---------------- fused attention aggregation -------------------------------
__global__ __launch_bounds__(256, 4) void aggregate_kernel(
    const u16* __restrict__ srcp, const u16* __restrict__ dstp,
    const int* __restrict__ row_start, const int* __restrict__ srclist,
    const float* __restrict__ x, const float* __restrict__ attn,
    const float* __restrict__ bias, const float* __restrict__ palpha,
    const float* __restrict__ ww, const float* __restrict__ bw,
    float* __restrict__ outp, float* __restrict__ weighted)
{
  const int wv = threadIdx.x >> 6;
  const int lane = threadIdx.x & 63;
  const int half = lane >> 5;
  const int l32 = lane & 31;
  const int h = lane & 7;
  const int es = (lane >> 3) & 3;
  const int i = (blockIdx.x * 4 + wv) * 2 + half;
  const uint4* sp = (const uint4*)srcp;

  f2 d2[8], a2[8];
  {
    const uint4 dA = ((const uint4*)dstp)[(size_t)i * 16 + h * 2];
    const uint4 dB = ((const uint4*)dstp)[(size_t)i * 16 + h * 2 + 1];
    d2[0]=unpk(dA.x); d2[1]=unpk(dA.y); d2[2]=unpk(dA.z); d2[3]=unpk(dA.w);
    d2[4]=unpk(dB.x); d2[5]=unpk(dB.y); d2[6]=unpk(dB.z); d2[7]=unpk(dB.w);
    const float4* ap = (const float4*)attn + h * 4;
    #pragma unroll
    for (int q = 0; q < 4; ++q){
      const float4 vv = ap[q];
      a2[2*q].x = vv.x; a2[2*q].y = vv.y; a2[2*q+1].x = vv.z; a2[2*q+1].y = vv.w;
    }
  }
  const int lo = row_start[i], hi = row_start[i + 1];
  const int deg = hi - lo;
  int myidx = 0;
  if (l32 < deg) myidx = srclist[lo + l32];
  const int nb = (deg + 3) >> 2;

  f2 acc2[8];
  #pragma unroll
  for (int k = 0; k < 8; ++k){ acc2[k].x = 0.f; acc2[k].y = 0.f; }
  float denom = 0.f;

  auto FETCH = [&](int k, uint4& A, uint4& B, bool& v){
    const int il = k * 4 + es;
    v = il < deg;
    int s;
    if (il < 32) s = __shfl(myidx, half * 32 + il);
    else         s = v ? srclist[lo + il] : 0;
    if (!v) s = 0;
    const uint4* rp = sp + (size_t)s * 16 + h * 2;
    A = rp[0]; B = rp[1];
  };

  uint4 cA, cB, nA, nB, mA, mB;
  bool cv = false, nv = false, mv = false;
  if (nb > 0) FETCH(0, cA, cB, cv);
  if (nb > 1) FETCH(1, nA, nB, nv);
  for (int k = 0; k < nb; ++k){
    if (k + 2 < nb) FETCH(k + 2, mA, mB, mv); else mv = false;
    f2 sv[8];
    sv[0]=unpk(cA.x); sv[1]=unpk(cA.y); sv[2]=unpk(cA.z); sv[3]=unpk(cA.w);
    sv[4]=unpk(cB.x); sv[5]=unpk(cB.y); sv[6]=unpk(cB.z); sv[7]=unpk(cB.w);
    f2 p; p.x = 0.f; p.y = 0.f;
    #pragma unroll
    for (int q = 0; q < 8; ++q){
      f2 e = sv[q] + d2[q];
      e = vmax2(e, e * 0.2f);
      p += e * a2[q];
    }
    float w = cv ? __expf(p.x + p.y) : 0.f;
    denom += w;
    f2 w2; w2.x = w; w2.y = w;
    #pragma unroll
    for (int q = 0; q < 8; ++q) acc2[q] += sv[q] * w2;
    cA = nA; cB = nB; cv = nv;
    nA = mA; nB = mB; nv = mv;
  }
  #pragma unroll
  for (int m = 8; m <= 16; m <<= 1){
    #pragma unroll
    for (int q = 0; q < 8; ++q){
      acc2[q].x += __shfl_xor(acc2[q].x, m);
      acc2[q].y += __shfl_xor(acc2[q].y, m);
    }
    denom += __shfl_xor(denom, m);
  }
  const float inv = 1.f / (denom + 1e-16f);

  const float al = palpha[0];
  float o[16];
  {
    const float4* xp = (const float4*)x + (size_t)i * 32 + h * 4;
    const float4* bp = (const float4*)bias + h * 4;
    #pragma unroll
    for (int q = 0; q < 4; ++q){
      const float4 xv = xp[q];
      const float4 bv = bp[q];
      float t0 = fmaf(acc2[2*q].x,   inv, xv.x) + bv.x;
      float t1 = fmaf(acc2[2*q].y,   inv, xv.y) + bv.y;
      float t2 = fmaf(acc2[2*q+1].x, inv, xv.z) + bv.z;
      float t3 = fmaf(acc2[2*q+1].y, inv, xv.w) + bv.w;
      o[4*q]   = (t0 > 0.f) ? t0 : al * t0;
      o[4*q+1] = (t1 > 0.f) ? t1 : al * t1;
      o[4*q+2] = (t2 > 0.f) ? t2 : al * t2;
      o[4*q+3] = (t3 > 0.f) ? t3 : al * t3;
    }
  }
  if (es == 0){
    float4* op = (float4*)outp + (size_t)i * 32 + h * 4;
    #pragma unroll
    for (int q = 0; q < 4; ++q){
      float4 vv; vv.x = o[4*q]; vv.y = o[4*q+1]; vv.z = o[4*q+2]; vv.w = o[4*q+3];
      op[q] = vv;
    }
  }
  float z = 0.f;
  {
    const float4* gp = (const float4*)ww + h * 4;
    #pragma unroll
    for (int q = 0; q < 4; ++q){
      const float4 gv = gp[q];
      z = fmaf(o[4*q], gv.x, z); z = fmaf(o[4*q+1], gv.y, z);
      z = fmaf(o[4*q+2], gv.z, z); z = fmaf(o[4*q+3], gv.w, z);
    }
  }
  z += __shfl_xor(z, 1);
  z += __shfl_xor(z, 2);
  z += __shfl_xor(z, 4);
  if (l32 == 0){
    z += bw[0];
    weighted[i] = 1.f / (1.f + __expf(-z));
  }
}

// ---------------- readout: one block per graph -------------------------------
__global__ __launch_bounds__(256) void readout_kernel(
    const float* __restrict__ outp, const float* __restrict__ weighted,
    const int* __restrict__ batchv, const float* __restrict__ wscore,
    const float* __restrict__ bscore, float* __restrict__ ro)
{
  __shared__ int range_s[2];
  __shared__ float wsum_s[128];
  __shared__ float max_s[128];
  __shared__ float wtot_s[2];
  __shared__ float part_s[256];
  const int g = blockIdx.x, t = threadIdx.x;
  const int col = t & 127, grp = t >> 7;
  if (t < 2){
    const int target = g + t;
    int lo = 0, hi = NODES;
    while (lo < hi){ const int m = (lo + hi) >> 1; if (batchv[m] < target) lo = m + 1; else hi = m; }
    range_s[t] = lo;
  }
  __syncthreads();
  const int lo = range_s[0], hi = range_s[1];
  float acc = 0.f, vmax = -INFINITY, wacc = 0.f;
  for (int n = lo + grp; n < hi; n += 2){
    const float w = weighted[n];
    const float v = outp[n * 128 + col];
    acc = fmaf(w, v, acc);
    vmax = fmaxf(vmax, v);
    if (col == 0) wacc += w;
  }
  part_s[t] = acc;
  if (col == 0) wtot_s[grp] = wacc;
  __syncthreads();
  if (grp == 0) wsum_s[col] = acc + part_s[col + 128];
  __syncthreads();
  part_s[t] = vmax;
  __syncthreads();
  if (grp == 0) max_s[col] = fmaxf(vmax, part_s[col + 128]);
  const float wtot = wtot_s[0] + wtot_s[1];
  __syncthreads();
  float dot = 0.f;
  const float* wr = wscore + col * 128 + grp * 64;
  const float* xs = wsum_s + grp * 64;
  #pragma unroll
  for (int k = 0; k < 64; ++k) dot = fmaf(wr[k], xs[k], dot);
  part_s[t] = dot;
  __syncthreads();
  if (grp == 0){
    const float s = dot + part_s[col + 128] + wtot * bscore[col];
    ro[g * 256 + col] = s;
    ro[g * 256 + 128 + col] = max_s[col];
  }
}

extern "C" void kernel_launch(void* const* d_in, const int* in_sizes, int n_in,
                              void* d_out, int out_size, void* d_ws, size_t ws_size,
                              hipStream_t stream)
{
  const float* x      = (const float*)d_in[0];
  const int*   ei     = (const int*)d_in[1];
  const int*   batchv = (const int*)d_in[2];
  const float* Wsrc   = (const float*)d_in[3];
  const float* Wdst   = (const float*)d_in[4];
  const float* attn   = (const float*)d_in[5];
  const float* bias   = (const float*)d_in[6];
  const float* palpha = (const float*)d_in[7];
  const float* ww     = (const float*)d_in[8];
  const float* bw     = (const float*)d_in[9];
  const float* wsc    = (const float*)d_in[10];
  const float* bsc    = (const float*)d_in[11];

  char* ws = (char*)d_ws;
  u16*  srcp      = (u16*) (ws + 0);          // 12,800,000 B (packed bf16)
  u16*  dstp      = (u16*) (ws + 12800000);   // 12,800,000 B
  int*  srclist   = (int*) (ws + 25600000);   //  3,200,000 B
  int*  row_start = (int*) (ws + 28800000);   //    200,004 B
  int*  bcount    = (int*) (ws + 29000192);   //    153,664 B (NB*ABLK)
  int*  bstart    = (int*) (ws + 29153856);   //        788 B
  float* weighted = (float*)(ws + 29154688);  //    200,000 B

  float* outp = (float*)d_out;                // [N,128] fp32
  float* ro = outp + NODES * FEAT;            // [G,256] fp32
  u32* ebuf = (u32*)d_out;                    // scratch alias: dead until aggregate

  proj_kernel<<<782, 256, 0, stream>>>(x, Wsrc, Wdst, srcp, dstp);
  bucket_hist_kernel<<<ABLK, 256, 0, stream>>>(ei, bcount);
  bucket_scan_kernel<<<1, 256, 0, stream>>>(bcount, bstart);
  bucket_scatter_kernel<<<ABLK, 256, 0, stream>>>(ei, bcount, bstart, ebuf);
  bucket_csr_kernel<<<NB, 256, 0, stream>>>(ebuf, bstart, row_start, srclist);
  aggregate_kernel<<<6250, 256, 0, stream>>>(srcp, dstp, row_start, srclist,
                                             x, attn, bias, palpha, ww, bw,
                                             outp, weighted);
  readout_kernel<<<GRAPHS, 256, 0, stream>>>(outp, weighted, batchv, wsc, bsc, ro);
}

// Round 10
// 221.215 us; speedup vs baseline: 1.1012x; 1.1012x over previous
//
#include <hip/hip_runtime.h>

#define NODES 50000
#define FEAT 128
#define EDGES 800000
#define GRAPHS 512
#define NB 196      // dst buckets (dst >> 8), 196*256 = 50176 >= NODES
#define CHUNK 4096
#define ABLK 196    // ceil(EDGES/CHUNK)
#define BCAP 8192   // max edges per bucket (mean 4082, max ~4400)
#define PROJ_BLOCKS 782

typedef unsigned int u32;
typedef unsigned short u16;
typedef __attribute__((ext_vector_type(8))) short short8;   // 8 bf16 = 4 VGPRs
typedef __attribute__((ext_vector_type(4))) float v4f;      // MFMA accumulator
typedef __attribute__((ext_vector_type(4))) u32 u32x4;
typedef __attribute__((ext_vector_type(2))) float f2;       // packed-fp32 pair

static __device__ __forceinline__ float bflo(u32 u){ return __uint_as_float(u << 16); }
static __device__ __forceinline__ float bfhi(u32 u){ return __uint_as_float(u & 0xffff0000u); }
static __device__ __forceinline__ u16 f2bf(float f){
  u32 u = __float_as_uint(f);
  u32 r = u + 0x7fffu + ((u >> 16) & 1u);
  return (u16)(r >> 16);
}
static __device__ __forceinline__ u32 packbf(float a, float b){
  return (u32)f2bf(a) | ((u32)f2bf(b) << 16);
}
static __device__ __forceinline__ f2 unpk(u32 u){ f2 r; r.x = bflo(u); r.y = bfhi(u); return r; }
static __device__ __forceinline__ f2 vmax2(f2 a, f2 b){ f2 r; r.x = fmaxf(a.x,b.x); r.y = fmaxf(a.y,b.y); return r; }

// ---------------- fused: MFMA projection (blocks 0..781) + bucket hist -------
// proj = R8's v2 (LDS-staged x, register B-frags, both matrices per block).
// hist blocks (782..977) are independent and hide behind proj.
#define LROW 68
__global__ __launch_bounds__(256) void proj_hist_kernel(
    const float* __restrict__ x, const float* __restrict__ Wsrc,
    const float* __restrict__ Wdst, u16* __restrict__ srcp, u16* __restrict__ dstp,
    const int* __restrict__ ei, int* __restrict__ bcount)
{
  __shared__ u32 x_lds[64 * LROW];
  __shared__ int cnt[NB];
  const int t = threadIdx.x;

  if (blockIdx.x >= PROJ_BLOCKS){
    // ---- histogram role ----
    const int b = blockIdx.x - PROJ_BLOCKS;
    for (int k = t; k < NB; k += 256) cnt[k] = 0;
    __syncthreads();
    const int e0 = b * CHUNK;
    const int e1 = (e0 + CHUNK < EDGES) ? e0 + CHUNK : EDGES;
    for (int e = e0 + t; e < e1; e += 256)
      atomicAdd(&cnt[ei[EDGES + e] >> 8], 1);
    __syncthreads();
    for (int k = t; k < NB; k += 256) bcount[k * ABLK + b] = cnt[k];
    return;
  }

  // ---- projection role ----
  const int node0 = blockIdx.x * 64;
  const int rows_valid = NODES - node0 < 64 ? NODES - node0 : 64;
  const float4* xp = (const float4*)(x + (size_t)node0 * 128);
  for (int idx = t; idx < rows_valid * 32; idx += 256){
    const float4 v = xp[idx];
    const int row = idx >> 5, cq = idx & 31;
    x_lds[row * LROW + cq * 2]     = packbf(v.x, v.y);
    x_lds[row * LROW + cq * 2 + 1] = packbf(v.z, v.w);
  }

  const int wave = t >> 6, lane = t & 63;
  const int r16 = lane & 15;
  const int quad = lane >> 4;
  const int ko = quad * 4;
  const int n0 = wave * 32;

  short8 bs[2][4], bd[2][4];
  #pragma unroll
  for (int nt = 0; nt < 2; ++nt){
    const int col = n0 + nt * 16 + r16;
    #pragma unroll
    for (int k = 0; k < 4; ++k){
      const float4* wp = (const float4*)(Wsrc + col * 128 + quad * 8 + k * 32);
      float4 w0 = wp[0], w1 = wp[1];
      u32x4 pk; pk.x = packbf(w0.x,w0.y); pk.y = packbf(w0.z,w0.w);
      pk.z = packbf(w1.x,w1.y); pk.w = packbf(w1.z,w1.w);
      bs[nt][k] = __builtin_bit_cast(short8, pk);
      const float4* vp = (const float4*)(Wdst + col * 128 + quad * 8 + k * 32);
      float4 v0 = vp[0], v1 = vp[1];
      u32x4 qk; qk.x = packbf(v0.x,v0.y); qk.y = packbf(v0.z,v0.w);
      qk.z = packbf(v1.x,v1.y); qk.w = packbf(v1.z,v1.w);
      bd[nt][k] = __builtin_bit_cast(short8, qk);
    }
  }
  __syncthreads();

  #pragma unroll
  for (int mt = 0; mt < 4; ++mt){
    const int node_base = node0 + mt * 16;
    if (node_base >= NODES) break;
    short8 afr[4];
    #pragma unroll
    for (int k = 0; k < 4; ++k)
      afr[k] = *(const short8*)&x_lds[(mt * 16 + r16) * LROW + ko + k * 16];
    v4f s0 = {0.f,0.f,0.f,0.f}, s1 = s0, d0 = s0, d1 = s0;
    #pragma unroll
    for (int k = 0; k < 4; ++k){
      s0 = __builtin_amdgcn_mfma_f32_16x16x32_bf16(afr[k], bs[0][k], s0, 0, 0, 0);
      s1 = __builtin_amdgcn_mfma_f32_16x16x32_bf16(afr[k], bs[1][k], s1, 0, 0, 0);
      d0 = __builtin_amdgcn_mfma_f32_16x16x32_bf16(afr[k], bd[0][k], d0, 0, 0, 0);
      d1 = __builtin_amdgcn_mfma_f32_16x16x32_bf16(afr[k], bd[1][k], d1, 0, 0, 0);
    }
    // C/D layout: col = lane&15, row = quad*4 + reg  [verified m89/m91]
    u16* so = srcp + (size_t)(node_base + quad * 4) * 128 + n0 + r16;
    u16* do_ = dstp + (size_t)(node_base + quad * 4) * 128 + n0 + r16;
    #pragma unroll
    for (int r = 0; r < 4; ++r){
      so[r * 128]      = f2bf(s0[r]);
      so[r * 128 + 16] = f2bf(s1[r]);
      do_[r * 128]      = f2bf(d0[r]);
      do_[r * 128 + 16] = f2bf(d1[r]);
    }
  }
}

// ---------------- scatter with inline scan -----------------------------------
// Each block re-derives per-bucket totals/prefixes from raw bcount (L2-resident).
// Block 0 publishes bstart to global for bucket_csr_kernel.
__global__ __launch_bounds__(256) void bucket_scatter_kernel(
    const int* __restrict__ ei, const int* __restrict__ bcount,
    int* __restrict__ bstart_g, u32* __restrict__ ebuf)
{
  __shared__ int tot[256];
  __shared__ int bstart_s[NB + 1];
  __shared__ int obase_s[NB];
  __shared__ int cur[NB];
  const int b = blockIdx.x, t = threadIdx.x;
  int total = 0, obase = 0;
  if (t < NB){
    const int* row = bcount + t * ABLK;
    int run = 0;
    for (int q = 0; q < ABLK; ++q){
      if (q == b) obase = run;
      run += row[q];
    }
    total = run;
  }
  tot[t] = total;
  __syncthreads();
  const int v = total;
  for (int off = 1; off < 256; off <<= 1){
    const int add = (t >= off) ? tot[t - off] : 0;
    __syncthreads();
    tot[t] += add;
    __syncthreads();
  }
  if (t < NB){
    bstart_s[t] = tot[t] - v;
    obase_s[t] = obase;
    cur[t] = 0;
  }
  if (t == NB - 1) bstart_s[NB] = tot[t];
  __syncthreads();
  if (b == 0 && t <= NB) bstart_g[t] = bstart_s[t];

  const int e0 = b * CHUNK;
  const int e1 = (e0 + CHUNK < EDGES) ? e0 + CHUNK : EDGES;
  for (int e = e0 + t; e < e1; e += 256){
    const int d = ei[EDGES + e];
    const int s = ei[e];
    const int k = d >> 8;
    const int r = atomicAdd(&cur[k], 1);
    ebuf[bstart_s[k] + obase_s[k] + r] = (u32)s | ((u32)(d & 255) << 16);
  }
}

// ---------------- B4: one block per bucket: local CSR in LDS -----------------
__global__ __launch_bounds__(256) void bucket_csr_kernel(
    const u32* __restrict__ ebuf, const int* __restrict__ bstart,
    int* __restrict__ row_start, int* __restrict__ srclist)
{
  __shared__ int cnt[256], excl[256], cur[256];
  __shared__ u32 loc[BCAP];
  const int k = blockIdx.x, t = threadIdx.x;
  const int base = bstart[k];
  int ne = bstart[k + 1] - base;
  if (ne > BCAP) ne = BCAP;
  cnt[t] = 0;
  __syncthreads();
  for (int j = t; j < ne; j += 256)
    atomicAdd(&cnt[(ebuf[base + j] >> 16) & 255], 1);
  __syncthreads();
  const int v = cnt[t];
  for (int off = 1; off < 256; off <<= 1){
    const int add = (t >= off) ? cnt[t - off] : 0;
    __syncthreads();
    cnt[t] += add;
    __syncthreads();
  }
  excl[t] = cnt[t] - v;
  cur[t] = cnt[t] - v;
  __syncthreads();
  const int node = k * 256 + t;
  if (node <= NODES) row_start[node] = base + excl[t];
  for (int j = t; j < ne; j += 256){
    const u32 e = ebuf[base + j];
    const int p = atomicAdd(&cur[(e >> 16) & 255], 1);
    loc[p] = e & 0xFFFFu;
  }
  __syncthreads();
  for (int j = t; j < ne; j += 256)
    srclist[base + j] = (int)loc[j];
}

// ---------------- fused attention aggregation -------------------------------
__global__ __launch_bounds__(256, 4) void aggregate_kernel(
    const u16* __restrict__ srcp, const u16* __restrict__ dstp,
    const int* __restrict__ row_start, const int* __restrict__ srclist,
    const float* __restrict__ x, const float* __restrict__ attn,
    const float* __restrict__ bias, const float* __restrict__ palpha,
    const float* __restrict__ ww, const float* __restrict__ bw,
    float* __restrict__ outp, float* __restrict__ weighted)
{
  const int wv = threadIdx.x >> 6;
  const int lane = threadIdx.x & 63;
  const int half = lane >> 5;
  const int l32 = lane & 31;
  const int h = lane & 7;
  const int es = (lane >> 3) & 3;
  const int i = (blockIdx.x * 4 + wv) * 2 + half;
  const uint4* sp = (const uint4*)srcp;

  f2 d2[8], a2[8];
  {
    const uint4 dA = ((const uint4*)dstp)[(size_t)i * 16 + h * 2];
    const uint4 dB = ((const uint4*)dstp)[(size_t)i * 16 + h * 2 + 1];
    d2[0]=unpk(dA.x); d2[1]=unpk(dA.y); d2[2]=unpk(dA.z); d2[3]=unpk(dA.w);
    d2[4]=unpk(dB.x); d2[5]=unpk(dB.y); d2[6]=unpk(dB.z); d2[7]=unpk(dB.w);
    const float4* ap = (const float4*)attn + h * 4;
    #pragma unroll
    for (int q = 0; q < 4; ++q){
      const float4 vv = ap[q];
      a2[2*q].x = vv.x; a2[2*q].y = vv.y; a2[2*q+1].x = vv.z; a2[2*q+1].y = vv.w;
    }
  }
  const int lo = row_start[i], hi = row_start[i + 1];
  const int deg = hi - lo;
  int myidx = 0;
  if (l32 < deg) myidx = srclist[lo + l32];
  const int nb = (deg + 3) >> 2;

  f2 acc2[8];
  #pragma unroll
  for (int k = 0; k < 8; ++k){ acc2[k].x = 0.f; acc2[k].y = 0.f; }
  float denom = 0.f;

  auto FETCH = [&](int k, uint4& A, uint4& B, bool& v){
    const int il = k * 4 + es;
    v = il < deg;
    int s;
    if (il < 32) s = __shfl(myidx, half * 32 + il);
    else         s = v ? srclist[lo + il] : 0;
    if (!v) s = 0;
    const uint4* rp = sp + (size_t)s * 16 + h * 2;
    A = rp[0]; B = rp[1];
  };

  uint4 cA, cB, nA, nB, mA, mB;
  bool cv = false, nv = false, mv = false;
  if (nb > 0) FETCH(0, cA, cB, cv);
  if (nb > 1) FETCH(1, nA, nB, nv);
  for (int k = 0; k < nb; ++k){
    if (k + 2 < nb) FETCH(k + 2, mA, mB, mv); else mv = false;
    f2 sv[8];
    sv[0]=unpk(cA.x); sv[1]=unpk(cA.y); sv[2]=unpk(cA.z); sv[3]=unpk(cA.w);
    sv[4]=unpk(cB.x); sv[5]=unpk(cB.y); sv[6]=unpk(cB.z); sv[7]=unpk(cB.w);
    f2 p; p.x = 0.f; p.y = 0.f;
    #pragma unroll
    for (int q = 0; q < 8; ++q){
      f2 e = sv[q] + d2[q];
      e = vmax2(e, e * 0.2f);
      p += e * a2[q];
    }
    float w = cv ? __expf(p.x + p.y) : 0.f;
    denom += w;
    f2 w2; w2.x = w; w2.y = w;
    #pragma unroll
    for (int q = 0; q < 8; ++q) acc2[q] += sv[q] * w2;
    cA = nA; cB = nB; cv = nv;
    nA = mA; nB = mB; nv = mv;
  }
  #pragma unroll
  for (int m = 8; m <= 16; m <<= 1){
    #pragma unroll
    for (int q = 0; q < 8; ++q){
      acc2[q].x += __shfl_xor(acc2[q].x, m);
      acc2[q].y += __shfl_xor(acc2[q].y, m);
    }
    denom += __shfl_xor(denom, m);
  }
  const float inv = 1.f / (denom + 1e-16f);

  const float al = palpha[0];
  float o[16];
  {
    const float4* xp = (const float4*)x + (size_t)i * 32 + h * 4;
    const float4* bp = (const float4*)bias + h * 4;
    #pragma unroll
    for (int q = 0; q < 4; ++q){
      const float4 xv = xp[q];
      const float4 bv = bp[q];
      float t0 = fmaf(acc2[2*q].x,   inv, xv.x) + bv.x;
      float t1 = fmaf(acc2[2*q].y,   inv, xv.y) + bv.y;
      float t2 = fmaf(acc2[2*q+1].x, inv, xv.z) + bv.z;
      float t3 = fmaf(acc2[2*q+1].y, inv, xv.w) + bv.w;
      o[4*q]   = (t0 > 0.f) ? t0 : al * t0;
      o[4*q+1] = (t1 > 0.f) ? t1 : al * t1;
      o[4*q+2] = (t2 > 0.f) ? t2 : al * t2;
      o[4*q+3] = (t3 > 0.f) ? t3 : al * t3;
    }
  }
  if (es == 0){
    float4* op = (float4*)outp + (size_t)i * 32 + h * 4;
    #pragma unroll
    for (int q = 0; q < 4; ++q){
      float4 vv; vv.x = o[4*q]; vv.y = o[4*q+1]; vv.z = o[4*q+2]; vv.w = o[4*q+3];
      op[q] = vv;
    }
  }
  float z = 0.f;
  {
    const float4* gp = (const float4*)ww + h * 4;
    #pragma unroll
    for (int q = 0; q < 4; ++q){
      const float4 gv = gp[q];
      z = fmaf(o[4*q], gv.x, z); z = fmaf(o[4*q+1], gv.y, z);
      z = fmaf(o[4*q+2], gv.z, z); z = fmaf(o[4*q+3], gv.w, z);
    }
  }
  z += __shfl_xor(z, 1);
  z += __shfl_xor(z, 2);
  z += __shfl_xor(z, 4);
  if (l32 == 0){
    z += bw[0];
    weighted[i] = 1.f / (1.f + __expf(-z));
  }
}

// ---------------- readout: one block per graph -------------------------------
__global__ __launch_bounds__(256) void readout_kernel(
    const float* __restrict__ outp, const float* __restrict__ weighted,
    const int* __restrict__ batchv, const float* __restrict__ wscore,
    const float* __restrict__ bscore, float* __restrict__ ro)
{
  __shared__ int range_s[2];
  __shared__ float wsum_s[128];
  __shared__ float max_s[128];
  __shared__ float wtot_s[2];
  __shared__ float part_s[256];
  const int g = blockIdx.x, t = threadIdx.x;
  const int col = t & 127, grp = t >> 7;
  if (t < 2){
    const int target = g + t;
    int lo = 0, hi = NODES;
    while (lo < hi){ const int m = (lo + hi) >> 1; if (batchv[m] < target) lo = m + 1; else hi = m; }
    range_s[t] = lo;
  }
  __syncthreads();
  const int lo = range_s[0], hi = range_s[1];
  float acc = 0.f, vmax = -INFINITY, wacc = 0.f;
  for (int n = lo + grp; n < hi; n += 2){
    const float w = weighted[n];
    const float v = outp[n * 128 + col];
    acc = fmaf(w, v, acc);
    vmax = fmaxf(vmax, v);
    if (col == 0) wacc += w;
  }
  part_s[t] = acc;
  if (col == 0) wtot_s[grp] = wacc;
  __syncthreads();
  if (grp == 0) wsum_s[col] = acc + part_s[col + 128];
  __syncthreads();
  part_s[t] = vmax;
  __syncthreads();
  if (grp == 0) max_s[col] = fmaxf(vmax, part_s[col + 128]);
  const float wtot = wtot_s[0] + wtot_s[1];
  __syncthreads();
  float dot = 0.f;
  const float* wr = wscore + col * 128 + grp * 64;
  const float* xs = wsum_s + grp * 64;
  #pragma unroll
  for (int k = 0; k < 64; ++k) dot = fmaf(wr[k], xs[k], dot);
  part_s[t] = dot;
  __syncthreads();
  if (grp == 0){
    const float s = dot + part_s[col + 128] + wtot * bscore[col];
    ro[g * 256 + col] = s;
    ro[g * 256 + 128 + col] = max_s[col];
  }
}

extern "C" void kernel_launch(void* const* d_in, const int* in_sizes, int n_in,
                              void* d_out, int out_size, void* d_ws, size_t ws_size,
                              hipStream_t stream)
{
  const float* x      = (const float*)d_in[0];
  const int*   ei     = (const int*)d_in[1];
  const int*   batchv = (const int*)d_in[2];
  const float* Wsrc   = (const float*)d_in[3];
  const float* Wdst   = (const float*)d_in[4];
  const float* attn   = (const float*)d_in[5];
  const float* bias   = (const float*)d_in[6];
  const float* palpha = (const float*)d_in[7];
  const float* ww     = (const float*)d_in[8];
  const float* bw     = (const float*)d_in[9];
  const float* wsc    = (const float*)d_in[10];
  const float* bsc    = (const float*)d_in[11];

  char* ws = (char*)d_ws;
  u16*  srcp      = (u16*) (ws + 0);          // 12,800,000 B (packed bf16)
  u16*  dstp      = (u16*) (ws + 12800000);   // 12,800,000 B
  int*  srclist   = (int*) (ws + 25600000);   //  3,200,000 B
  int*  row_start = (int*) (ws + 28800000);   //    200,004 B
  int*  bcount    = (int*) (ws + 29000192);   //    153,664 B (NB*ABLK)
  int*  bstart    = (int*) (ws + 29153856);   //        788 B
  float* weighted = (float*)(ws + 29154688);  //    200,000 B

  float* outp = (float*)d_out;                // [N,128] fp32
  float* ro = outp + NODES * FEAT;            // [G,256] fp32
  u32* ebuf = (u32*)d_out;                    // scratch alias: dead until aggregate

  proj_hist_kernel<<<PROJ_BLOCKS + ABLK, 256, 0, stream>>>(
      x, Wsrc, Wdst, srcp, dstp, ei, bcount);
  bucket_scatter_kernel<<<ABLK, 256, 0, stream>>>(ei, bcount, bstart, ebuf);
  bucket_csr_kernel<<<NB, 256, 0, stream>>>(ebuf, bstart, row_start, srclist);
  aggregate_kernel<<<6250, 256, 0, stream>>>(srcp, dstp, row_start, srclist,
                                             x, attn, bias, palpha, ww, bw,
                                             outp, weighted);
  readout_kernel<<<GRAPHS, 256, 0, stream>>>(outp, weighted, batchv, wsc, bsc, ro);
}